// Round 3
// baseline (19492.372 us; speedup 1.0000x reference)
//
#include <hip/hip_runtime.h>
#include <cstdint>
#include <cstddef>

#define T_LEN 8192
#define EMB 256
#define HD 256          // hidden per direction
#define G4 1024         // 4*HD
#define NT 16
#define START_IX 14
#define STOP_IX 15

// ---------------------------------------------------------------------------
// Phase A: xw[dir][t][r] = emb[dir? T-1-t : t] @ w_ih^T + (b_ih + b_hh)
// grid (T/32, G4/128, 2), block 256   (unchanged — not yet the bottleneck)
// ---------------------------------------------------------------------------
__global__ __launch_bounds__(256) void k_gemm_xw(
    const int* __restrict__ sent, const float* __restrict__ embed,
    const float* __restrict__ wih_f, const float* __restrict__ wih_b,
    const float* __restrict__ bih_f, const float* __restrict__ bhh_f,
    const float* __restrict__ bih_b, const float* __restrict__ bhh_b,
    float* __restrict__ xw)
{
    const int dir = blockIdx.z;
    const float* __restrict__ wih = dir ? wih_b : wih_f;
    const float* __restrict__ bih = dir ? bih_b : bih_f;
    const float* __restrict__ bhh = dir ? bhh_b : bhh_f;
    __shared__ float at[32][65];
    __shared__ float bt[128][65];
    const int t0 = blockIdx.x * 32, r0 = blockIdx.y * 128;
    const int tid = threadIdx.x;
    const int tx = tid & 31, ty = tid >> 5;
    float acc[4][4] = {};
    for (int k0 = 0; k0 < EMB; k0 += 64) {
        for (int i = tid; i < 32 * 64; i += 256) {
            int row = i >> 6, k = i & 63;
            int t = t0 + row;
            int ts = dir ? (T_LEN - 1 - t) : t;
            at[row][k] = embed[(size_t)sent[ts] * EMB + k0 + k];
        }
        for (int i = tid; i < 128 * 64; i += 256) {
            int row = i >> 6, k = i & 63;
            bt[row][k] = wih[(size_t)(r0 + row) * EMB + k0 + k];
        }
        __syncthreads();
#pragma unroll 16
        for (int kc = 0; kc < 64; ++kc) {
            float a[4], b[4];
#pragma unroll
            for (int u = 0; u < 4; ++u) a[u] = at[ty * 4 + u][kc];
#pragma unroll
            for (int u = 0; u < 4; ++u) b[u] = bt[tx * 4 + u][kc];
#pragma unroll
            for (int u = 0; u < 4; ++u)
#pragma unroll
                for (int v = 0; v < 4; ++v) acc[u][v] += a[u] * b[v];
        }
        __syncthreads();
    }
#pragma unroll
    for (int u = 0; u < 4; ++u) {
        int t = t0 + ty * 4 + u;
#pragma unroll
        for (int v = 0; v < 4; ++v) {
            int r = r0 + tx * 4 + v;
            xw[((size_t)dir * T_LEN + t) * G4 + r] = acc[u][v] + bih[r] + bhh[r];
        }
    }
}

// ---------------------------------------------------------------------------
// Phase B: LSTM scans. grid 16 (= dir*8 + w), block 512 (8 waves).
// Exchange v3: private tagged mailboxes. mbox[dir][cons][parity][prod][32]
// u64 words = (step_tag << 32) | float_bits. Exactly one writer wave and one
// reader wave per cache line pair -> no line contention. Parity (t&1) +
// B2 barrier bound producer/consumer skew to <2 steps -> no overwrite race,
// no per-step resets. memset(0xFF) once per launch kills cross-replay ABA.
// Roles per step (after B1):
//   wave 0          : reduce partials, gates (half-split + shfl_xor pair),
//                     c/h update, h_lds own slice, h_hist + 7 mailbox stores
//   waves 1-7 lo32  : poll private mailbox line of slice s -> h_lds
//   waves 1-4 hi32  : prefetch xw[t+1] -> xw_lds[nxt]
// ---------------------------------------------------------------------------
__global__ __launch_bounds__(512) void k_lstm(
    const float* __restrict__ whh_f, const float* __restrict__ whh_b,
    const float* __restrict__ h0, const float* __restrict__ c0,
    const float* __restrict__ xw, float* __restrict__ h_hist,
    unsigned long long* __restrict__ mbox)
{
    const int dir = blockIdx.x >> 3;
    const int w = blockIdx.x & 7;
    const float* __restrict__ whh = dir ? whh_b : whh_f;
    const int tid = threadIdx.x;
    const int q = tid >> 7;        // k-quarter 0..3
    const int r = tid & 127;       // local gate-row 0..127
    const int R = (r >> 5) * 256 + w * 32 + (r & 31);   // global gate-row

    __shared__ float h_lds[256];
    __shared__ float partial[512];
    __shared__ float xw_lds[2][128];

    float4 wreg[16];
    {
        const float4* wp = (const float4*)&whh[(size_t)R * HD + q * 64];
#pragma unroll
        for (int u = 0; u < 16; ++u) wreg[u] = wp[u];
    }

    if (tid < 256) h_lds[tid] = h0[dir * HD + tid];
    if (tid < 128)
        xw_lds[0][tid] = xw[((size_t)dir * T_LEN) * G4
                            + (tid >> 5) * 256 + w * 32 + (tid & 31)];

    const int wave = tid >> 6;
    const int lane = tid & 63;
    const int j = lane & 31, half = lane >> 5;
    float c = 0.f;
    if (wave == 0) c = c0[dir * HD + w * 32 + j];   // both halves keep c

    int ps = 0;                                     // polled slice for waves 1-7
    if (wave >= 1) ps = (wave - 1) + ((wave - 1) >= w ? 1 : 0);

    __syncthreads();

    float* __restrict__ hh = h_hist + (size_t)dir * T_LEN * HD;

    for (int t = 0; t < T_LEN; ++t) {
        const int cur = t & 1, nxt = cur ^ 1;

        // matvec partial, 4 independent accumulator chains
        float a0 = 0.f, a1 = 0.f, a2 = 0.f, a3 = 0.f;
        const float4* hp = (const float4*)&h_lds[q * 64];
#pragma unroll
        for (int u = 0; u < 4; ++u) {
            float4 hv0 = hp[u * 4 + 0], hv1 = hp[u * 4 + 1];
            float4 hv2 = hp[u * 4 + 2], hv3 = hp[u * 4 + 3];
            float4 wv0 = wreg[u * 4 + 0], wv1 = wreg[u * 4 + 1];
            float4 wv2 = wreg[u * 4 + 2], wv3 = wreg[u * 4 + 3];
            a0 += wv0.x * hv0.x + wv0.y * hv0.y + wv0.z * hv0.z + wv0.w * hv0.w;
            a1 += wv1.x * hv1.x + wv1.y * hv1.y + wv1.z * hv1.z + wv1.w * hv1.w;
            a2 += wv2.x * hv2.x + wv2.y * hv2.y + wv2.z * hv2.z + wv2.w * hv2.w;
            a3 += wv3.x * hv3.x + wv3.y * hv3.y + wv3.z * hv3.z + wv3.w * hv3.w;
        }
        partial[q * 128 + r] = (a0 + a1) + (a2 + a3);
        __syncthreads();   // B1

        if (wave == 0) {
            // lane j: gates i,f ; lane j+32: gates g,o ; pair via shfl_xor(32)
            const int rA = half * 64 + j, rB = rA + 32;
            float zA = xw_lds[cur][rA] + partial[rA] + partial[128 + rA]
                     + partial[256 + rA] + partial[384 + rA];
            float zB = xw_lds[cur][rB] + partial[rB] + partial[128 + rB]
                     + partial[256 + rB] + partial[384 + rB];
            float gA, gB;
            if (half == 0) { gA = 1.f / (1.f + expf(-zA));
                             gB = 1.f / (1.f + expf(-zB)); }       // i, f
            else           { gA = tanhf(zA);
                             gB = 1.f / (1.f + expf(-zB)); }       // g, o
            float xA = __shfl_xor(gA, 32);
            float xB = __shfl_xor(gB, 32);
            float iv = half ? xA : gA;
            float fv = half ? xB : gB;
            float gv = half ? gA : xA;
            float ov = half ? gB : xB;
            c = fv * c + iv * gv;                  // identical in both halves
            float hv = ov * tanhf(c);
            h_lds[w * 32 + j] = hv;
            unsigned long long pkt = ((unsigned long long)(unsigned)t << 32)
                                   | (unsigned long long)__float_as_uint(hv);
            if (half == 0) {
                hh[(size_t)t * HD + w * 32 + j] = hv;
#pragma unroll
                for (int cons = 0; cons < 4; ++cons)
                    if (cons != w)
                        __hip_atomic_store(
                            &mbox[((((size_t)dir * 8 + cons) * 2 + cur) * 8 + w) * 32 + j],
                            pkt, __ATOMIC_RELAXED, __HIP_MEMORY_SCOPE_AGENT);
            } else {
#pragma unroll
                for (int cons = 4; cons < 8; ++cons)
                    if (cons != w)
                        __hip_atomic_store(
                            &mbox[((((size_t)dir * 8 + cons) * 2 + cur) * 8 + w) * 32 + j],
                            pkt, __ATOMIC_RELAXED, __HIP_MEMORY_SCOPE_AGENT);
            }
        } else {
            if (half == 0) {
                // private line: only this wave reads it, only producer ps writes
                const unsigned long long* src =
                    &mbox[((((size_t)dir * 8 + w) * 2 + cur) * 8 + ps) * 32 + j];
                unsigned long long u; int spin = 0;
                do {
                    u = __hip_atomic_load(src, __ATOMIC_RELAXED,
                                          __HIP_MEMORY_SCOPE_AGENT);
                } while ((unsigned)(u >> 32) != (unsigned)t && ++spin < (1 << 20));
                h_lds[ps * 32 + j] = __uint_as_float((unsigned)u);
            } else if (wave <= 4) {
                const int row = (wave - 1) * 32 + j;
                if (t + 1 < T_LEN)
                    xw_lds[nxt][row] = xw[((size_t)dir * T_LEN + (t + 1)) * G4
                                          + (row >> 5) * 256 + w * 32 + (row & 31)];
            }
        }
        __syncthreads();   // B2
    }
}

// ---------------------------------------------------------------------------
// Phase C: feats[t][tag] = [hs_f[t], hs_b[t]] . W_out[tag] + b_out[tag]
// ---------------------------------------------------------------------------
__global__ __launch_bounds__(256) void k_feats(
    const float* __restrict__ h_hist, const float* __restrict__ Wout,
    const float* __restrict__ bout, float* __restrict__ feats)
{
    int idx = blockIdx.x * 256 + threadIdx.x;
    int tag = idx & 15, t = idx >> 4;
    const float4* hf = (const float4*)(h_hist + (size_t)t * HD);
    const float4* hb = (const float4*)(h_hist + (size_t)(T_LEN + (T_LEN - 1 - t)) * HD);
    const float4* w0 = (const float4*)(Wout + (size_t)tag * 512);
    const float4* w1 = w0 + 64;
    float acc = bout[tag];
    for (int k = 0; k < 64; ++k) {
        float4 a = hf[k], b = w0[k];
        acc += a.x * b.x + a.y * b.y + a.z * b.z + a.w * b.w;
    }
    for (int k = 0; k < 64; ++k) {
        float4 a = hb[k], b = w1[k];
        acc += a.x * b.x + a.y * b.y + a.z * b.z + a.w * b.w;
    }
    feats[(size_t)t * NT + tag] = acc;
}

// ---------------------------------------------------------------------------
// Phase D: Viterbi. Forward now register-resident fv + __shfl (no LDS round
// trips), fp64, 2-deep feats prefetch. Backtrack: map-composition suffix scan.
// ---------------------------------------------------------------------------
__device__ __forceinline__ unsigned bsel16(uint4 g, unsigned e) {
    unsigned wd = (e < 8u) ? ((e < 4u) ? g.x : g.y) : ((e < 12u) ? g.z : g.w);
    return (wd >> ((e & 3u) * 8u)) & 15u;
}

__global__ __launch_bounds__(256) void k_viterbi(
    const float* __restrict__ feats, const float* __restrict__ trans,
    int* __restrict__ out, unsigned char* __restrict__ bp)
{
    __shared__ int sid;
    __shared__ unsigned slo[512], shi[512];
    const int tid = threadIdx.x;

    if (tid < 64) {
        const int i = tid & 15, jg = tid >> 4;
        double tr[4];
#pragma unroll
        for (int u = 0; u < 4; ++u) tr[u] = (double)trans[i * 16 + jg * 4 + u];
        double fvn = (i == START_IX) ? 0.0 : -10000.0;   // live in lanes 0-15
        float fA = feats[i];
        float fB = feats[16 + i];

        for (int t = 0; t < T_LEN; ++t) {
            float fC = (t + 2 < T_LEN) ? feats[(size_t)(t + 2) * NT + i] : 0.f;

            double best = -1e300; int bj = 0;
#pragma unroll
            for (int u = 0; u < 4; ++u) {
                double fvv = __shfl(fvn, jg * 4 + u);
                double v = fvv + tr[u];
                if (v > best) { best = v; bj = jg * 4 + u; }   // first-max
            }
            double ob = __shfl_down(best, 32); int oj = __shfl_down(bj, 32);
            if (ob > best || (ob == best && oj < bj)) { best = ob; bj = oj; }
            ob = __shfl_down(best, 16); oj = __shfl_down(bj, 16);
            if (ob > best || (ob == best && oj < bj)) { best = ob; bj = oj; }

            if (tid < 16) {
                bp[(size_t)t * 16 + i] = (unsigned char)bj;
                fvn = (double)fA + best;
            }
            fA = fB; fB = fC;
        }
        double term = (tid < 16) ? fvn + (double)trans[tid * 16 + STOP_IX] : -1e300;
        int ti = tid;
#pragma unroll
        for (int off = 1; off < 16; off <<= 1) {
            double ov = __shfl_xor(term, off); int oi = __shfl_xor(ti, off);
            if (ov > term || (ov == term && oi < ti)) { term = ov; ti = oi; }
        }
        if (tid == 0) sid = ti;
    }
    __syncthreads();

    // backtrack: suffix scan of composed backpointer maps
    const int j = tid;
    unsigned Flo = 0x76543210u, Fhi = 0xfedcba98u;
    for (int t = 32 * j + 31; t >= 32 * j; --t) {
        uint4 g = *(const uint4*)&bp[(size_t)t * 16];
        unsigned nlo = 0, nhi = 0;
#pragma unroll
        for (int x = 0; x < 8; ++x) {
            unsigned e = (Flo >> (x * 4)) & 15u;
            nlo |= bsel16(g, e) << (x * 4);
        }
#pragma unroll
        for (int x = 0; x < 8; ++x) {
            unsigned e = (Fhi >> (x * 4)) & 15u;
            nhi |= bsel16(g, e) << (x * 4);
        }
        Flo = nlo; Fhi = nhi;
    }
    slo[j] = Flo; shi[j] = Fhi;
    slo[j + 256] = 0x76543210u; shi[j + 256] = 0xfedcba98u;
    __syncthreads();
    for (int off = 1; off < 256; off <<= 1) {
        unsigned alo = slo[j], ahi = shi[j];
        unsigned blo = slo[j + off], bhi = shi[j + off];
        __syncthreads();
        unsigned nlo = 0, nhi = 0;
#pragma unroll
        for (int x = 0; x < 8; ++x) {
            unsigned e = (blo >> (x * 4)) & 15u;
            unsigned rr = ((e < 8u ? alo : ahi) >> ((e & 7u) * 4u)) & 15u;
            nlo |= rr << (x * 4);
        }
#pragma unroll
        for (int x = 0; x < 8; ++x) {
            unsigned e = (bhi >> (x * 4)) & 15u;
            unsigned rr = ((e < 8u ? alo : ahi) >> ((e & 7u) * 4u)) & 15u;
            nhi |= rr << (x * 4);
        }
        slo[j] = nlo; shi[j] = nhi;
        __syncthreads();
    }
    int idl = sid;
    unsigned plo = slo[j + 1], phi = shi[j + 1];
    unsigned x = (((unsigned)idl < 8u ? plo : phi) >> (((unsigned)idl & 7u) * 4u)) & 15u;
    out[32 * j + 31] = (int)x;
    for (int t = 32 * j + 30; t >= 32 * j; --t) {
        x = (unsigned)bp[(size_t)(t + 1) * 16 + x];
        out[t] = (int)x;
    }
}

// ---------------------------------------------------------------------------
extern "C" void kernel_launch(void* const* d_in, const int* in_sizes, int n_in,
                              void* d_out, int out_size, void* d_ws, size_t ws_size,
                              hipStream_t stream) {
    const int*   sent  = (const int*)  d_in[0];
    const float* embed = (const float*)d_in[1];
    const float* wih_f = (const float*)d_in[2];
    const float* whh_f = (const float*)d_in[3];
    const float* bih_f = (const float*)d_in[4];
    const float* bhh_f = (const float*)d_in[5];
    const float* wih_b = (const float*)d_in[6];
    const float* whh_b = (const float*)d_in[7];
    const float* bih_b = (const float*)d_in[8];
    const float* bhh_b = (const float*)d_in[9];
    const float* Wout  = (const float*)d_in[10];
    const float* bout  = (const float*)d_in[11];
    const float* trans = (const float*)d_in[12];
    const float* h0    = (const float*)d_in[13];
    const float* c0    = (const float*)d_in[14];
    int* out = (int*)d_out;

    float* ws_xw   = (float*)d_ws;                                  // 2*T*1024 f
    float* ws_h    = ws_xw + (size_t)2 * T_LEN * G4;                // 2*T*256 f
    float* ws_feat = ws_h + (size_t)2 * T_LEN * HD;                 // T*16 f
    unsigned char* ws_bp = (unsigned char*)(ws_feat + (size_t)T_LEN * NT); // T*16 B
    unsigned long long* ws_mbox =
        (unsigned long long*)(ws_bp + (size_t)T_LEN * NT);          // 8192 u64

    // tag-poison mailboxes: 0xFFFFFFFF tag never matches any step id, and
    // re-running every launch kills cross-replay ABA.
    hipMemsetAsync(ws_mbox, 0xFF, (size_t)8192 * sizeof(unsigned long long), stream);

    dim3 gA(T_LEN / 32, G4 / 128, 2);
    k_gemm_xw<<<gA, 256, 0, stream>>>(sent, embed, wih_f, wih_b,
                                      bih_f, bhh_f, bih_b, bhh_b, ws_xw);
    k_lstm<<<16, 512, 0, stream>>>(whh_f, whh_b, h0, c0, ws_xw, ws_h, ws_mbox);
    k_feats<<<512, 256, 0, stream>>>(ws_h, Wout, bout, ws_feat);
    k_viterbi<<<1, 256, 0, stream>>>(ws_feat, trans, out, ws_bp);
}